// Round 13
// baseline (550.347 us; speedup 1.0000x reference)
//
#include <hip/hip_runtime.h>
#include <math.h>

#define NN 40000
#define EE 640000
#define DD 128
#define EDD 16
#define LL 3
#define TEB 64   // edges per block in edge_msg_kernel

__device__ __constant__ float kBnInv = 0.9999950000374997f; // 1/sqrt(1+1e-5)

typedef __bf16 bf16x8 __attribute__((ext_vector_type(8)));
typedef float  f32x4  __attribute__((ext_vector_type(4)));
typedef float  f32x2  __attribute__((ext_vector_type(2)));

// pack two floats to bf16 pair (RTNE) in one uint: lo16=a, hi16=b
__device__ __forceinline__ unsigned pack_bf2(float a, float b) {
    unsigned ua = __float_as_uint(a), ub = __float_as_uint(b);
    ua = (ua + 0x7fffu + ((ua >> 16) & 1u)) >> 16;
    ub = (ub + 0x7fffu + ((ub >> 16) & 1u)) & 0xffff0000u;
    return ua | ub;
}
__device__ __forceinline__ unsigned short bf16r(float x) {
    unsigned u = __float_as_uint(x);
    u = (u + 0x7fffu + ((u >> 16) & 1u)) >> 16;
    return (unsigned short)u;
}

// ---------------------------------------------------------------------------
// node encoder; emits hb (packed bf16), layer-0 pi/pj, z init (= (1+eps0)*h).
// fp32 h is dead downstream -> not stored.
__global__ __launch_bounds__(256) void node_enc_kernel(
    const float* __restrict__ x, const float* __restrict__ W,
    const float* __restrict__ b,
    const float* __restrict__ aW, const float* __restrict__ eps_p,
    unsigned* __restrict__ hb,
    float* __restrict__ pi, float* __restrict__ pj, float* __restrict__ z)
{
    __shared__ float xs[32][DD];
    const int t = threadIdx.x;
    const long rowbase = (long)blockIdx.x * 32;

    const float4* x4 = (const float4*)(x + rowbase * DD);
    float4* xs4 = (float4*)&xs[0][0];
#pragma unroll
    for (int i = 0; i < 4; i++) xs4[t + i * 256] = x4[t + i * 256];
    __syncthreads();

    const int c  = (t & 31) * 4;
    const int r0 = (t >> 5) * 4;

    float acc[4][4] = {};
    for (int k4 = 0; k4 < DD; k4 += 4) {
        float4 xr[4];
#pragma unroll
        for (int i = 0; i < 4; i++) xr[i] = *(const float4*)&xs[r0 + i][k4];
#pragma unroll
        for (int kk = 0; kk < 4; kk++) {
            const float4 w = *(const float4*)(W + (k4 + kk) * DD + c);
#pragma unroll
            for (int i = 0; i < 4; i++) {
                const float xv = ((const float*)&xr[i])[kk];
                acc[i][0] = fmaf(xv, w.x, acc[i][0]);
                acc[i][1] = fmaf(xv, w.y, acc[i][1]);
                acc[i][2] = fmaf(xv, w.z, acc[i][2]);
                acc[i][3] = fmaf(xv, w.w, acc[i][3]);
            }
        }
    }
    const float4 bv  = *(const float4*)(b + c);
    const float4 awi = *(const float4*)(aW + c);
    const float4 awj = *(const float4*)(aW + DD + c);
    const float ep = 1.0f + eps_p[0];

    float pa[4], pb[4];
#pragma unroll
    for (int i = 0; i < 4; i++) {
        const long row = rowbase + r0 + i;
        float4 ov = { acc[i][0] + bv.x, acc[i][1] + bv.y,
                      acc[i][2] + bv.z, acc[i][3] + bv.w };
        uint2 pv = { pack_bf2(ov.x, ov.y), pack_bf2(ov.z, ov.w) };
        *(uint2*)(hb + row * 64 + (c >> 1)) = pv;
        float4 zv = { ep * ov.x, ep * ov.y, ep * ov.z, ep * ov.w };
        *(float4*)(z + row * DD + c) = zv;
        pa[i] = ov.x * awi.x + ov.y * awi.y + ov.z * awi.z + ov.w * awi.w;
        pb[i] = ov.x * awj.x + ov.y * awj.y + ov.z * awj.z + ov.w * awj.w;
    }
#pragma unroll
    for (int off = 1; off < 32; off <<= 1) {
#pragma unroll
        for (int i = 0; i < 4; i++) {
            pa[i] += __shfl_xor(pa[i], off, 64);
            pb[i] += __shfl_xor(pb[i], off, 64);
        }
    }
    if ((t & 31) == 0) {
#pragma unroll
        for (int i = 0; i < 4; i++) {
            pi[rowbase + r0 + i] = pa[i];
            pj[rowbase + r0 + i] = pb[i];
        }
    }
}

// ---------------------------------------------------------------------------
// weight transpose + bf16 cast
__global__ __launch_bounds__(256) void wcast_kernel(
    const float* __restrict__ W1, const float* __restrict__ W2,
    unsigned short* __restrict__ w1t, unsigned short* __restrict__ w2t)
{
    const int idx = blockIdx.x * 256 + threadIdx.x;   // grid covers LL*32768
    const int l = idx >> 15, r = idx & 32767;
    {   const int n = r >> 7, k = r & 127;
        w1t[idx] = bf16r(W1[(l << 15) + (k << 8) + n]);
    }
    {   const int n = r >> 8, k = r & 255;
        w2t[idx] = bf16r(W2[(l << 15) + (k << 7) + n]);
    }
}

// ---------------------------------------------------------------------------
// CSR build
__global__ __launch_bounds__(256) void hist_kernel(
    const int* __restrict__ edge_index, int* __restrict__ counts)
{
    const int i = blockIdx.x * 256 + threadIdx.x;
    atomicAdd(&counts[edge_index[EE + i]], 1);
}

__global__ __launch_bounds__(256) void scan1_kernel(
    const int* __restrict__ counts, int* __restrict__ scanned,
    int* __restrict__ partials)
{
    __shared__ int sdata[256];
    const int t = threadIdx.x;
    const int base = blockIdx.x * 1024 + t * 4;
    int v[4]; int sum = 0;
#pragma unroll
    for (int i = 0; i < 4; i++) {
        const int idx = base + i;
        v[i] = (idx < NN) ? counts[idx] : 0;
        sum += v[i];
    }
    sdata[t] = sum;
    __syncthreads();
    for (int off = 1; off < 256; off <<= 1) {
        int x = (t >= off) ? sdata[t - off] : 0;
        __syncthreads();
        sdata[t] += x;
        __syncthreads();
    }
    int run = sdata[t] - sum;
#pragma unroll
    for (int i = 0; i < 4; i++) {
        const int idx = base + i;
        if (idx < NN) scanned[idx] = run;
        run += v[i];
    }
    if (t == 255) partials[blockIdx.x] = sdata[255];
}

__global__ void scan2_kernel(int* __restrict__ partials)
{
    if (threadIdx.x == 0) {
        int run = 0;
        for (int i = 0; i < 40; i++) { int v = partials[i]; partials[i] = run; run += v; }
    }
}

__global__ __launch_bounds__(256) void scan3_kernel(
    const int* __restrict__ scanned, const int* __restrict__ partials,
    int* __restrict__ offsets, int* __restrict__ cursor)
{
    const int idx = blockIdx.x * 256 + threadIdx.x;
    if (idx < NN) {
        const int off = scanned[idx] + partials[idx >> 10];
        offsets[idx] = off;
        cursor[idx]  = off;
    }
}

// scatter: pre-scaled src/dst streams + fp32 edge_attr at CSR position
// (sequential reads, scattered 64 B writes; fp32 so edge_msg can s_load it).
__global__ __launch_bounds__(256) void scatter_kernel(
    const int* __restrict__ edge_index, const float* __restrict__ edge_attr,
    int* __restrict__ cursor,
    int* __restrict__ srcs_p, int* __restrict__ dstd_p,
    float* __restrict__ ea_p)
{
    const int i = blockIdx.x * 256 + threadIdx.x;
    const int src = edge_index[i];
    const int dst = edge_index[EE + i];
    const int pos = atomicAdd(&cursor[dst], 1);
    srcs_p[pos] = src << 6;
    dstd_p[pos] = dst << 7;

    const float4* sp = (const float4*)(edge_attr + (long)i * EDD);
    float4* dp = (float4*)(ea_p + (long)pos * EDD);
    dp[0] = sp[0]; dp[1] = sp[1]; dp[2] = sp[2]; dp[3] = sp[3];
}

// ---------------------------------------------------------------------------
// LDS-staged edge aggregation. ea is NOT staged in LDS: it is wave-uniform
// per edge, so the consume loop reads it through a readfirstlane-uniformized
// pointer (-> s_load via scalar cache, off the LDS pipe). LDS ~17 KB ->
// 8 blocks/CU. Meta read from LDS in b128 chunks of 4 edges.
__global__ __launch_bounds__(256) void edge_msg_kernel(
    const unsigned* __restrict__ hb, const float* __restrict__ ea_p,
    const float* __restrict__ pi, const float* __restrict__ pj,
    const int* __restrict__ srcs_p, const int* __restrict__ dstd_p,
    const float* __restrict__ ab_p,
    const float* __restrict__ eW, const float* __restrict__ eb,
    float* __restrict__ z)
{
    __shared__ unsigned sh_hb[TEB * 64];               // 16 KB
    __shared__ int      sh_src[TEB];
    __shared__ __align__(16) int   sh_dst[TEB];
    __shared__ __align__(16) float sh_a[TEB];

    const int t = threadIdx.x;
    const long e0 = (long)blockIdx.x * TEB;            // grid = EE/TEB

    // ---- meta stage + fused attention coefficient ----
    if (t < TEB) {
        const int ss = srcs_p[e0 + t];
        const int dd = dstd_p[e0 + t];
        sh_src[t] = ss;
        sh_dst[t] = dd;
        const float s = pi[dd >> 7] + pj[ss >> 6] + ab_p[0];
        sh_a[t] = 1.0f / (1.0f + expf(-s));
    }
    __syncthreads();

    // ---- gather stage (coalesced, 4 independent 16B gathers/thread) ----
    {
        const int chunk = t & 15;
        const int r0    = t >> 4;
#pragma unroll
        for (int i = 0; i < TEB / 16; i++) {
            const int row  = r0 + 16 * i;
            const int srow = sh_src[row];              // src*64 (dword index)
            *(uint4*)&sh_hb[row * 64 + chunk * 4] =
                *(const uint4*)(hb + srow + chunk * 4);
        }
    }
    __syncthreads();

    // ---- consume ----
    const int wid = t >> 6, lane = t & 63;
    const int c0 = lane * 2;
    const int base = wid * (TEB / 4);                  // 16 edges per wave

    f32x2 ew[EDD];
#pragma unroll
    for (int q = 0; q < EDD; q++) {
        const float2 w2 = ((const float2*)(eW + q * DD))[lane];
        ew[q][0] = w2.x; ew[q][1] = w2.y;
    }
    const float2 ebf = ((const float2*)eb)[lane];
    const f32x2 ebv = { ebf.x, ebf.y };
    const f32x2 zero2 = { 0.0f, 0.0f };

    f32x2 acc = zero2;
    int cur = sh_dst[base];
    // wave-uniform edge index for scalar ea loads
    const int ebase_s = __builtin_amdgcn_readfirstlane((int)e0 + base);

#pragma unroll 2
    for (int j4 = 0; j4 < TEB / 4; j4 += 4) {
        const int4   dd4 = *(const int4*)&sh_dst[base + j4];
        const float4 aa4 = *(const float4*)&sh_a[base + j4];
        const int   dd[4] = { dd4.x, dd4.y, dd4.z, dd4.w };
        const float aa[4] = { aa4.x, aa4.y, aa4.z, aa4.w };
#pragma unroll
        for (int r = 0; r < 4; r++) {
            const int j = j4 + r;
            const unsigned u = sh_hb[(base + j) * 64 + lane];
            // uniform pointer -> s_load_dwordx4 x4 (scalar cache)
            const float4* eap = (const float4*)(ea_p + (long)(ebase_s + j) * EDD);
            const float4 t0 = eap[0], t1 = eap[1], t2 = eap[2], t3 = eap[3];
            const float ea[EDD] = { t0.x,t0.y,t0.z,t0.w, t1.x,t1.y,t1.z,t1.w,
                                    t2.x,t2.y,t2.z,t2.w, t3.x,t3.y,t3.z,t3.w };
            f32x2 ev = ebv;
#pragma unroll
            for (int q = 0; q < EDD; q++) {
                const f32x2 eaq = { ea[q], ea[q] };
                ev = __builtin_elementwise_fma(eaq, ew[q], ev);
            }

            if (dd[r] != cur) {                        // wave-uniform branch
                atomicAdd(&z[cur + c0],     acc[0]);
                atomicAdd(&z[cur + c0 + 1], acc[1]);
                acc = zero2; cur = dd[r];
            }
            const f32x2 xj = { __uint_as_float(u << 16),
                               __uint_as_float(u & 0xffff0000u) };
            const f32x2 av = { aa[r], aa[r] };
            f32x2 m = __builtin_elementwise_fma(xj, av, ev);
            m = __builtin_elementwise_max(m, zero2);
            acc += m;
        }
    }
    atomicAdd(&z[cur + c0],     acc[0]);
    atomicAdd(&z[cur + c0 + 1], acc[1]);
}

// ---------------------------------------------------------------------------
// Fused GIN MLP via bf16 MFMA, N-split (wave owns col-tiles for all 64 rows).
// Intermediate layers: write hb + next-layer pi/pj/z only (fp32 out is dead).
// Final layer: write out only.
__global__ __launch_bounds__(256) void mlp_mfma_kernel(
    const float* __restrict__ zin,
    const unsigned short* __restrict__ w1t, const unsigned short* __restrict__ w2t,
    const float* __restrict__ b1, const float* __restrict__ g1, const float* __restrict__ bb1,
    const float* __restrict__ b2, const float* __restrict__ g2, const float* __restrict__ bb2,
    const float* __restrict__ aWn, const float* __restrict__ epsn_p,
    float* __restrict__ out, unsigned* __restrict__ hb,
    float* __restrict__ pi, float* __restrict__ pj, float* __restrict__ z,
    const int do_relu)
{
    __shared__ __align__(16) unsigned short zsb[64][136];   // 128 + 8 pad
    __shared__ __align__(16) unsigned short usb[64][264];   // 256 + 8 pad
    __shared__ float sh_pi[64], sh_pj[64];
    const int t = threadIdx.x;
    const int wid = t >> 6, lane = t & 63;
    const long rowbase = (long)blockIdx.x * 64;

    if (t < 64) { sh_pi[t] = 0.0f; sh_pj[t] = 0.0f; }

    // stage z (fp32) -> zsb (bf16)
    {
        const float4* z4 = (const float4*)(zin + rowbase * DD);
#pragma unroll
        for (int i = 0; i < 8; i++) {
            const int idx = t + i * 256;          // 2048 float4 = 64x128
            const float4 v = z4[idx];
            const int row = idx >> 5;
            const int c4  = (idx & 31) * 4;
            uint2 pv = { pack_bf2(v.x, v.y), pack_bf2(v.z, v.w) };
            *(uint2*)&zsb[row][c4] = pv;
        }
    }
    __syncthreads();

    const int mrow  = lane & 15;
    const int quad  = lane >> 4;
    const f32x4 vzero = {0.0f, 0.0f, 0.0f, 0.0f};

    // ---- phase 1: wave owns nt = wid*4 .. wid*4+3 (cols) for all 64 rows ----
    {
        const int nt0 = wid * 4;
        bf16x8 bf[4][4];                      // [j][ks]
#pragma unroll
        for (int j = 0; j < 4; j++) {
            const unsigned short* wp = w1t + ((nt0 + j) * 16 + mrow) * 128 + quad * 8;
#pragma unroll
            for (int ks = 0; ks < 4; ks++)
                bf[j][ks] = *(const bf16x8*)(wp + ks * 32);
        }
        float gg[4], bi[4], bt[4];
#pragma unroll
        for (int j = 0; j < 4; j++) {
            const int c = (nt0 + j) * 16 + mrow;
            gg[j] = g1[c]; bi[j] = b1[c]; bt[j] = bb1[c];
        }
#pragma unroll
        for (int rt = 0; rt < 4; rt++) {
            bf16x8 af[4];
#pragma unroll
            for (int ks = 0; ks < 4; ks++)
                af[ks] = *(const bf16x8*)&zsb[rt * 16 + mrow][ks * 32 + quad * 8];
            f32x4 acc[4];
#pragma unroll
            for (int j = 0; j < 4; j++) acc[j] = vzero;
#pragma unroll
            for (int j = 0; j < 4; j++)
#pragma unroll
                for (int ks = 0; ks < 4; ks++)
                    acc[j] = __builtin_amdgcn_mfma_f32_16x16x32_bf16(af[ks], bf[j][ks], acc[j], 0, 0, 0);
#pragma unroll
            for (int j = 0; j < 4; j++) {
                const int c = (nt0 + j) * 16 + mrow;
#pragma unroll
                for (int r = 0; r < 4; r++) {
                    const int row = rt * 16 + quad * 4 + r;
                    const float u = fmaxf(fmaf(gg[j] * (acc[j][r] + bi[j]), kBnInv, bt[j]), 0.0f);
                    const float up = __shfl_xor(u, 1, 64);
                    if ((mrow & 1) == 0)
                        *(unsigned*)&usb[row][c] = pack_bf2(u, up);
                }
            }
        }
    }
    __syncthreads();

    // ---- phase 2: wave owns nt = wid*2, wid*2+1 for all 64 rows ----
    {
        const int nt0 = wid * 2;
        bf16x8 bf[2][8];
#pragma unroll
        for (int j = 0; j < 2; j++) {
            const unsigned short* wp = w2t + ((nt0 + j) * 16 + mrow) * 256 + quad * 8;
#pragma unroll
            for (int ks = 0; ks < 8; ks++)
                bf[j][ks] = *(const bf16x8*)(wp + ks * 32);
        }
        float gg[2], bi[2], bt[2], awi[2], awj[2];
#pragma unroll
        for (int j = 0; j < 2; j++) {
            const int c = (nt0 + j) * 16 + mrow;
            gg[j] = g2[c]; bi[j] = b2[c]; bt[j] = bb2[c];
            awi[j] = aWn[c]; awj[j] = aWn[DD + c];
        }
        const float epn = do_relu ? (1.0f + epsn_p[0]) : 0.0f;

#pragma unroll
        for (int rt = 0; rt < 4; rt++) {
            bf16x8 af[8];
#pragma unroll
            for (int ks = 0; ks < 8; ks++)
                af[ks] = *(const bf16x8*)&usb[rt * 16 + mrow][ks * 32 + quad * 8];
            f32x4 acc[2];
            acc[0] = vzero; acc[1] = vzero;
#pragma unroll
            for (int j = 0; j < 2; j++)
#pragma unroll
                for (int ks = 0; ks < 8; ks++)
                    acc[j] = __builtin_amdgcn_mfma_f32_16x16x32_bf16(af[ks], bf[j][ks], acc[j], 0, 0, 0);

            float si[4] = {0, 0, 0, 0}, sj[4] = {0, 0, 0, 0};
#pragma unroll
            for (int j = 0; j < 2; j++) {
                const int c = (nt0 + j) * 16 + mrow;
#pragma unroll
                for (int r = 0; r < 4; r++) {
                    const long row = rowbase + rt * 16 + quad * 4 + r;
                    float v = fmaf(gg[j] * (acc[j][r] + bi[j]), kBnInv, bt[j]);
                    if (do_relu) {
                        v = fmaxf(v, 0.0f);
                        z[row * DD + c] = epn * v;
                        si[r] = fmaf(v, awi[j], si[r]);
                        sj[r] = fmaf(v, awj[j], sj[r]);
                        const float vp = __shfl_xor(v, 1, 64);
                        if ((mrow & 1) == 0)
                            hb[row * 64 + (c >> 1)] = pack_bf2(v, vp);
                    } else {
                        out[row * DD + c] = v;   // final layer only
                    }
                }
            }
            if (do_relu) {
#pragma unroll
                for (int off = 1; off < 16; off <<= 1) {
#pragma unroll
                    for (int r = 0; r < 4; r++) {
                        si[r] += __shfl_xor(si[r], off, 64);
                        sj[r] += __shfl_xor(sj[r], off, 64);
                    }
                }
                if (mrow == 0) {
#pragma unroll
                    for (int r = 0; r < 4; r++) {
                        atomicAdd(&sh_pi[rt * 16 + quad * 4 + r], si[r]);
                        atomicAdd(&sh_pj[rt * 16 + quad * 4 + r], sj[r]);
                    }
                }
            }
        }
    }
    if (do_relu) {
        __syncthreads();
        if (t < 64) {
            pi[rowbase + t] = sh_pi[t];
            pj[rowbase + t] = sh_pj[t];
        }
    }
}

// ---------------------------------------------------------------------------
extern "C" void kernel_launch(void* const* d_in, const int* in_sizes, int n_in,
                              void* d_out, int out_size, void* d_ws, size_t ws_size,
                              hipStream_t stream)
{
    const float* x         = (const float*)d_in[0];
    const float* edge_attr = (const float*)d_in[1];
    const float* node_W    = (const float*)d_in[2];
    const float* node_b    = (const float*)d_in[3];
    const float* edge_W    = (const float*)d_in[4];
    const float* edge_b    = (const float*)d_in[5];
    const float* attn_W    = (const float*)d_in[6];
    const float* attn_b    = (const float*)d_in[7];
    const float* eps       = (const float*)d_in[8];
    const float* W1        = (const float*)d_in[9];
    const float* b1        = (const float*)d_in[10];
    const float* bn1_g     = (const float*)d_in[11];
    const float* bn1_b     = (const float*)d_in[12];
    const float* W2        = (const float*)d_in[13];
    const float* b2        = (const float*)d_in[14];
    const float* bn_g      = (const float*)d_in[15];
    const float* bn_b      = (const float*)d_in[16];
    const int*   edge_index= (const int*)d_in[17];

    float* dummy = (float*)d_ws;                         // [N*D] (unused dst)
    float* z    = dummy + (size_t)NN * DD;               // [N*D]
    float* pi   = z + (size_t)NN * DD;                   // [N]
    float* pj   = pi + NN;                               // [N]
    float* ea_p = pj + NN;                               // [E*16] fp32 CSR order
    unsigned* hbuf = (unsigned*)(ea_p + (size_t)EE * EDD);           // [N*64]
    unsigned short* w1t = (unsigned short*)(hbuf + (size_t)NN * 64); // [L*32768]
    unsigned short* w2t = w1t + (size_t)LL * 32768;                  // [L*32768]
    int* counts  = (int*)(w2t + (size_t)LL * 32768);     // [N]
    int* offsets = counts + NN;                          // [N]
    int* cursor  = offsets + NN;                         // [N]
    int* scanned = cursor + NN;                          // [40960]
    int* partials= scanned + 40960;                      // [64]
    int* srcs_p  = partials + 64;                        // [E] (src*64)
    int* dstd_p  = srcs_p + EE;                          // [E] (dst*128)
    float* out = (float*)d_out;

    node_enc_kernel<<<NN / 32, 256, 0, stream>>>(
        x, node_W, node_b, attn_W, eps, hbuf, pi, pj, z);
    wcast_kernel<<<LL * 128, 256, 0, stream>>>(W1, W2, w1t, w2t);

    hipMemsetAsync(counts, 0, NN * sizeof(int), stream);
    hist_kernel<<<EE / 256, 256, 0, stream>>>(edge_index, counts);
    scan1_kernel<<<40, 256, 0, stream>>>(counts, scanned, partials);
    scan2_kernel<<<1, 64, 0, stream>>>(partials);
    scan3_kernel<<<(NN + 255) / 256, 256, 0, stream>>>(scanned, partials, offsets, cursor);
    scatter_kernel<<<EE / 256, 256, 0, stream>>>(
        edge_index, edge_attr, cursor, srcs_p, dstd_p, ea_p);

    for (int l = 0; l < LL; l++) {
        const int ln = (l + 1 < LL) ? (l + 1) : l;   // next-layer attn/eps (dummy at last)
        edge_msg_kernel<<<EE / TEB, 256, 0, stream>>>(
            hbuf, ea_p, pi, pj, srcs_p, dstd_p, attn_b + l,
            edge_W + (size_t)l * EDD * DD, edge_b + (size_t)l * DD, z);
        mlp_mfma_kernel<<<NN / 64, 256, 0, stream>>>(
            z,
            w1t + (size_t)l * 32768, w2t + (size_t)l * 32768,
            b1 + (size_t)l * 2 * DD, bn1_g + (size_t)l * 2 * DD, bn1_b + (size_t)l * 2 * DD,
            b2 + (size_t)l * DD, bn_g + (size_t)l * DD, bn_b + (size_t)l * DD,
            attn_W + (size_t)ln * 2 * DD, eps + ln,
            (l == LL - 1) ? out : dummy, hbuf, pi, pj, z, (l < LL - 1) ? 1 : 0);
    }
}